// Round 1
// baseline (978.965 us; speedup 1.0000x reference)
//
#include <hip/hip_runtime.h>
#include <stdint.h>

#define B_SZ 32
#define C_SZ 64
#define N_SZ 65536
#define K_SZ 8192

__device__ __forceinline__ uint32_t rotl32(uint32_t v, int r) {
  return (v << r) | (v >> (32 - r));
}

// JAX Threefry-2x32, 20 rounds.
__device__ __forceinline__ void threefry2x32(uint32_t k0, uint32_t k1,
                                             uint32_t x0, uint32_t x1,
                                             uint32_t& o0, uint32_t& o1) {
  const uint32_t ks2 = k0 ^ k1 ^ 0x1BD11BDAu;
  x0 += k0; x1 += k1;
#define TF_R(r) { x0 += x1; x1 = rotl32(x1, (r)); x1 ^= x0; }
  TF_R(13) TF_R(15) TF_R(26) TF_R(6)   x0 += k1;  x1 += ks2 + 1u;
  TF_R(17) TF_R(29) TF_R(16) TF_R(24)  x0 += ks2; x1 += k0  + 2u;
  TF_R(13) TF_R(15) TF_R(26) TF_R(6)   x0 += k0;  x1 += k1  + 3u;
  TF_R(17) TF_R(29) TF_R(16) TF_R(24)  x0 += k1;  x1 += ks2 + 4u;
  TF_R(13) TF_R(15) TF_R(26) TF_R(6)   x0 += ks2; x1 += k0  + 5u;
#undef TF_R
  o0 = x0; o1 = x1;
}

// subkey for batch b, shuffle round `round` (0 or 1), partitionable semantics:
//   keys = split(key(1), 32): keys[b] = threefry((0,1),(0,b))
//   per round: key,subkey = split(key): new key = threefry(key,(0,0)),
//                                       subkey  = threefry(key,(0,1))
__device__ __forceinline__ void subkey_for_round(int b, int round,
                                                 uint32_t& sk0, uint32_t& sk1) {
  uint32_t c0, c1;
  threefry2x32(0u, 1u, 0u, (uint32_t)b, c0, c1);
  for (int r = 0; r < round; ++r) {
    uint32_t n0, n1;
    threefry2x32(c0, c1, 0u, 0u, n0, n1);
    c0 = n0; c1 = n1;
  }
  threefry2x32(c0, c1, 0u, 1u, sk0, sk1);
}

// round-1 keys: pack (sortkey << 16) | position
__global__ void gen_round1(uint64_t* __restrict__ ping) {
  const int b = blockIdx.y;
  const int i = blockIdx.x * blockDim.x + threadIdx.x;
  uint32_t sk0, sk1, o0, o1;
  subkey_for_round(b, 0, sk0, sk1);
  threefry2x32(sk0, sk1, 0u, (uint32_t)i, o0, o1);
  const uint32_t bits = o0 ^ o1;  // partitionable 32-bit random bits
  ping[(size_t)b * N_SZ + i] = ((uint64_t)bits << 16) | (uint64_t)i;
}

// round-2 keys: value = round-1 sorted value at position i
__global__ void gen_round2(const uint64_t* __restrict__ sorted1,
                           uint64_t* __restrict__ out) {
  const int b = blockIdx.y;
  const int i = blockIdx.x * blockDim.x + threadIdx.x;
  uint32_t sk0, sk1, o0, o1;
  subkey_for_round(b, 1, sk0, sk1);
  threefry2x32(sk0, sk1, 0u, (uint32_t)i, o0, o1);
  const uint32_t bits = o0 ^ o1;
  const uint64_t val = sorted1[(size_t)b * N_SZ + i] & 0xFFFFull;
  out[(size_t)b * N_SZ + i] = ((uint64_t)bits << 16) | val;
}

// Stable 8-bit counting-sort pass over one batch per block.
// 256 threads; thread t owns contiguous chunk [t*256, t*256+256) in CURRENT
// order -> stability: positions assigned = binBase(d) + earlier-threads(d)
// + within-chunk order.
__global__ __launch_bounds__(256) void radix_pass(const uint64_t* __restrict__ in,
                                                  uint64_t* __restrict__ out,
                                                  int shift) {
  __shared__ uint16_t hist[256][256];   // [digit][thread], 128 KiB
  __shared__ uint32_t rowbase[256];
  const int b = blockIdx.x;
  const int t = threadIdx.x;
  const uint64_t* __restrict__ src = in + (size_t)b * N_SZ;
  uint64_t* __restrict__ dst = out + (size_t)b * N_SZ;

  for (int d = 0; d < 256; ++d) hist[d][t] = 0;
  __syncthreads();

  const int base = t * 256;
  for (int e = 0; e < 256; ++e) {
    const uint32_t dg = (uint32_t)(src[base + e] >> shift) & 0xFFu;
    hist[dg][t]++;
  }
  __syncthreads();

  // thread t: exclusive prefix within row (digit) t, row total -> rowbase[t]
  {
    uint32_t run = 0;
    for (int tt = 0; tt < 256; ++tt) {
      const uint32_t v = hist[t][tt];
      hist[t][tt] = (uint16_t)run;
      run += v;
    }
    rowbase[t] = run;
  }
  __syncthreads();
  if (t == 0) {
    uint32_t run = 0;
    for (int d = 0; d < 256; ++d) { const uint32_t v = rowbase[d]; rowbase[d] = run; run += v; }
  }
  __syncthreads();
  {
    const uint32_t bse = rowbase[t];
    for (int tt = 0; tt < 256; ++tt)
      hist[t][tt] = (uint16_t)(hist[t][tt] + bse);
  }
  __syncthreads();

  for (int e = 0; e < 256; ++e) {
    const uint64_t v = src[base + e];
    const uint32_t dg = (uint32_t)(v >> shift) & 0xFFu;
    const uint16_t pos = hist[dg][t]++;
    dst[pos] = v;
  }
}

__global__ void extract_idx(const uint64_t* __restrict__ sorted2,
                            uint32_t* __restrict__ idx) {
  const int b = blockIdx.y;
  const int k = blockIdx.x * blockDim.x + threadIdx.x;
  idx[(size_t)b * K_SZ + k] = (uint32_t)(sorted2[(size_t)b * N_SZ + k] & 0xFFFFull);
}

__global__ __launch_bounds__(256) void gather_kernel(const float* __restrict__ x,
                                                     const uint32_t* __restrict__ idx,
                                                     float* __restrict__ y) {
  const int k = blockIdx.x * 256 + threadIdx.x;  // 0..8191
  const int c = blockIdx.y;
  const int b = blockIdx.z;
  const uint32_t j = idx[(size_t)b * K_SZ + k];
  y[((size_t)(b * C_SZ + c)) * K_SZ + k] = x[((size_t)(b * C_SZ + c)) * N_SZ + j];
}

extern "C" void kernel_launch(void* const* d_in, const int* in_sizes, int n_in,
                              void* d_out, int out_size, void* d_ws, size_t ws_size,
                              hipStream_t stream) {
  (void)in_sizes; (void)n_in; (void)out_size; (void)ws_size;
  const float* x = (const float*)d_in[0];
  float* y = (float*)d_out;

  // Scratch layout: ping/pong (16 MB each) inside d_out (64 MB total);
  // final idx table (1 MB) in d_ws. Gather reads only x + idx, then
  // overwrites all of d_out.
  uint64_t* ping = (uint64_t*)d_out;
  uint64_t* pong = (uint64_t*)((char*)d_out + (size_t)B_SZ * N_SZ * sizeof(uint64_t));
  uint32_t* idx  = (uint32_t*)d_ws;

  const dim3 blk(256);
  const dim3 ggen(N_SZ / 256, B_SZ);

  hipLaunchKernelGGL(gen_round1, ggen, blk, 0, stream, ping);
  // round 1: sort key bits 0..31 == packed bits 16..47
  hipLaunchKernelGGL(radix_pass, dim3(B_SZ), blk, 0, stream, ping, pong, 16);
  hipLaunchKernelGGL(radix_pass, dim3(B_SZ), blk, 0, stream, pong, ping, 24);
  hipLaunchKernelGGL(radix_pass, dim3(B_SZ), blk, 0, stream, ping, pong, 32);
  hipLaunchKernelGGL(radix_pass, dim3(B_SZ), blk, 0, stream, pong, ping, 40);
  // ping = round-1 sorted
  hipLaunchKernelGGL(gen_round2, ggen, blk, 0, stream, ping, pong);
  hipLaunchKernelGGL(radix_pass, dim3(B_SZ), blk, 0, stream, pong, ping, 16);
  hipLaunchKernelGGL(radix_pass, dim3(B_SZ), blk, 0, stream, ping, pong, 24);
  hipLaunchKernelGGL(radix_pass, dim3(B_SZ), blk, 0, stream, pong, ping, 32);
  hipLaunchKernelGGL(radix_pass, dim3(B_SZ), blk, 0, stream, ping, pong, 40);
  // pong = round-2 sorted; first K entries' low 16 bits = idx[b]
  hipLaunchKernelGGL(extract_idx, dim3(K_SZ / 256, B_SZ), blk, 0, stream, pong, idx);
  hipLaunchKernelGGL(gather_kernel, dim3(K_SZ / 256, C_SZ, B_SZ), blk, 0, stream, x, idx, y);
}